// Round 1
// baseline (1234.189 us; speedup 1.0000x reference)
//
#include <hip/hip_runtime.h>
#include <math.h>

namespace {
constexpr int B_ = 2, CIN = 8, H_ = 224, W_ = 224;
constexpr int P_ = 10, K_ = 7, WIN_ = 3;
constexpr int F_ = 64, E_ = 8;
constexpr int N1 = 43, N2 = 43, N_ = N1 * N2;   // 1849
constexpr int M_ = 49;                           // candidates per query
constexpr int D_ = 800;                          // patch dim (C*P*P)
constexpr int HW = H_ * W_;

// workspace layout (floats)
constexpr size_t OFF_H1E = 0;
constexpr size_t OFF_H1T = OFF_H1E + (size_t)B_ * F_ * HW;
constexpr size_t OFF_H2E = OFF_H1T + (size_t)B_ * F_ * HW;
constexpr size_t OFF_H2T = OFF_H2E + (size_t)B_ * F_ * HW;
constexpr size_t OFF_NB  = 0;  // reuses h1/h2 region (free before attn runs)
constexpr size_t OFF_XE  = OFF_H2T + (size_t)B_ * F_ * HW;
constexpr size_t OFF_LTM = OFF_XE + (size_t)B_ * E_ * HW;
constexpr size_t OFF_PE  = OFF_LTM + (size_t)B_ * HW;
constexpr size_t OFF_YP  = OFF_PE + (size_t)B_ * N_ * D_;
constexpr size_t OFF_LT  = OFF_YP + (size_t)B_ * N_ * D_;
constexpr size_t OFF_SQ  = OFF_LT + (size_t)B_ * N_;
} // namespace

// ---------------------------------------------------------------------------
// Direct 3x3 SAME conv, NCHW. 32x32 spatial tile per block (16x16 threads,
// 2x2 pixels each), COG output channels per block, weights staged in LDS.
// ---------------------------------------------------------------------------
template <int CI, int COG, bool RELU>
__global__ __launch_bounds__(256) void conv3x3_k(
    const float* __restrict__ in, const float* __restrict__ wgt,
    const float* __restrict__ bias, float* __restrict__ out, int cout) {
  const int n_cog = cout / COG;
  const int b = blockIdx.z / n_cog;
  const int co0 = (blockIdx.z % n_cog) * COG;
  const int th0 = blockIdx.y * 32, tw0 = blockIdx.x * 32;
  const int tid = threadIdx.y * 16 + threadIdx.x;

  __shared__ float sW[COG * CI * 9];
  __shared__ float sT[34 * 34];

  for (int s = tid; s < COG * CI * 9; s += 256) {
    int c = s / (CI * 9), r = s - c * (CI * 9);
    sW[s] = wgt[(size_t)(co0 + c) * (CI * 9) + r];
  }

  float acc[COG][2][2];
#pragma unroll
  for (int c = 0; c < COG; ++c) {
    float bv = bias[co0 + c];
    acc[c][0][0] = bv; acc[c][0][1] = bv;
    acc[c][1][0] = bv; acc[c][1][1] = bv;
  }

  const int oy = 2 * threadIdx.y, ox = 2 * threadIdx.x;
  for (int ci = 0; ci < CI; ++ci) {
    const float* inp = in + ((size_t)b * CI + ci) * HW;
    __syncthreads();  // protects sT (prev iter readers) and sW (first iter)
    for (int s = tid; s < 34 * 34; s += 256) {
      int lr = s / 34, lc = s - lr * 34;
      int gh = th0 + lr - 1, gw = tw0 + lc - 1;
      float v = 0.f;
      if (gh >= 0 && gh < H_ && gw >= 0 && gw < W_) v = inp[gh * W_ + gw];
      sT[s] = v;
    }
    __syncthreads();
    float iv[4][4];
#pragma unroll
    for (int r = 0; r < 4; ++r)
#pragma unroll
      for (int c = 0; c < 4; ++c) iv[r][c] = sT[(oy + r) * 34 + ox + c];
#pragma unroll
    for (int c = 0; c < COG; ++c) {
      const float* wp = &sW[(c * CI + ci) * 9];
      float w0 = wp[0], w1 = wp[1], w2 = wp[2], w3 = wp[3], w4 = wp[4];
      float w5 = wp[5], w6 = wp[6], w7 = wp[7], w8 = wp[8];
#pragma unroll
      for (int dy = 0; dy < 2; ++dy)
#pragma unroll
        for (int dx = 0; dx < 2; ++dx) {
          acc[c][dy][dx] += iv[dy + 0][dx + 0] * w0 + iv[dy + 0][dx + 1] * w1 +
                            iv[dy + 0][dx + 2] * w2 + iv[dy + 1][dx + 0] * w3 +
                            iv[dy + 1][dx + 1] * w4 + iv[dy + 1][dx + 2] * w5 +
                            iv[dy + 2][dx + 0] * w6 + iv[dy + 2][dx + 1] * w7 +
                            iv[dy + 2][dx + 2] * w8;
        }
    }
  }

#pragma unroll
  for (int c = 0; c < COG; ++c)
#pragma unroll
    for (int dy = 0; dy < 2; ++dy)
#pragma unroll
      for (int dx = 0; dx < 2; ++dx) {
        int h = th0 + oy + dy, w = tw0 + ox + dx;
        float v = acc[c][dy][dx];
        if (RELU) v = fmaxf(v, 0.f);
        out[((size_t)b * cout + co0 + c) * HW + h * W_ + w] = v;
      }
}

// ---------------------------------------------------------------------------
// Patch extraction: dst[b, n, c*100 + i*10 + j] = src[b, c, 5*q1+i, 5*q2+j]
// ---------------------------------------------------------------------------
__global__ __launch_bounds__(256) void patches_k(const float* __restrict__ src,
                                                 float* __restrict__ dst) {
  int i = blockIdx.x * 256 + threadIdx.x;
  constexpr int TOT = B_ * N_ * D_;
  if (i >= TOT) return;
  int d = i % D_;
  int n = (i / D_) % N_;
  int b = i / (D_ * N_);
  int c = d / 100;
  int rr = (d / 10) % 10;
  int cc = d % 10;
  int q1 = n / N2, q2 = n % N2;
  dst[i] = src[((size_t)(b * 8 + c) * H_ + q1 * 5 + rr) * W_ + q2 * 5 + cc];
}

// ---------------------------------------------------------------------------
// Per-(b,n): sq = ||pe||^2 ; lt = mean of 10x10 log_temp patch.  1 wave each.
// ---------------------------------------------------------------------------
__global__ __launch_bounds__(64) void ltsq_k(const float* __restrict__ pe,
                                             const float* __restrict__ ltmap,
                                             float* __restrict__ lt,
                                             float* __restrict__ sq) {
  int bn = blockIdx.x;
  int b = bn / N_, n = bn % N_;
  int lane = threadIdx.x;
  const float* p = pe + (size_t)bn * D_;
  float s = 0.f;
  for (int i = lane; i < D_; i += 64) {
    float v = p[i];
    s += v * v;
  }
#pragma unroll
  for (int off = 32; off > 0; off >>= 1) s += __shfl_xor(s, off);
  int q1 = n / N2, q2 = n % N2;
  const float* lm = ltmap + (size_t)b * HW;
  float t = 0.f;
  for (int i = lane; i < 100; i += 64)
    t += lm[(q1 * 5 + i / 10) * W_ + q2 * 5 + i % 10];
#pragma unroll
  for (int off = 32; off > 0; off >>= 1) t += __shfl_xor(t, off);
  if (lane == 0) {
    sq[bn] = s;
    lt[bn] = t * 0.01f;
  }
}

// ---------------------------------------------------------------------------
// Per-(b,n) block: 49 dots -> logits -> K softmax iterations -> nb[k, b, n, :]
// ---------------------------------------------------------------------------
__global__ __launch_bounds__(256) void attn_k(const float* __restrict__ pe,
                                              const float* __restrict__ yp,
                                              const float* __restrict__ lt,
                                              const float* __restrict__ sq,
                                              float* __restrict__ nb) {
  const int n = blockIdx.x, b = blockIdx.y;
  const int tid = threadIdx.x;
  const int wave = tid >> 6, lane = tid & 63;

  __shared__ float sPe[D_];
  __shared__ float sLog[M_];
  __shared__ float sWk[M_ * K_];
  __shared__ int sIdx[M_];

  const int q1 = n / N2, q2 = n % N2;
  if (tid < M_) {
    int o1 = tid / 7 - WIN_, o2 = tid % 7 - WIN_;
    int c1 = min(max(q1 + o1, 0), N1 - 1);
    int c2 = min(max(q2 + o2, 0), N2 - 1);
    sIdx[tid] = c1 * N2 + c2;
  }
  const float* peB = pe + (size_t)b * N_ * D_;
  for (int s = tid; s < D_; s += 256) sPe[s] = peB[(size_t)n * D_ + s];
  __syncthreads();

  const float sq_n = sq[b * N_ + n];
  const float itemp = expf(-lt[b * N_ + n]);
  for (int m = wave; m < M_; m += 4) {
    const int cn = sIdx[m];
    const float* pc = peB + (size_t)cn * D_;
    float acc = 0.f;
    for (int s = lane; s < D_; s += 64) acc += sPe[s] * pc[s];
#pragma unroll
    for (int off = 32; off > 0; off >>= 1) acc += __shfl_xor(acc, off);
    if (lane == 0) {
      float Dv = -(sq_n + sq[b * N_ + cn] - 2.f * acc);
      float lg = Dv * itemp;
      if (cn == n) lg = -1e9f;
      sLog[m] = lg;
    }
  }
  __syncthreads();

  if (wave == 0) {
    float cur = (lane < M_) ? sLog[lane] : -INFINITY;
    for (int k = 0; k < K_; ++k) {
      float mx = cur;
#pragma unroll
      for (int off = 32; off > 0; off >>= 1) mx = fmaxf(mx, __shfl_xor(mx, off));
      float e = (lane < M_) ? expf(cur - mx) : 0.f;
      float ssum = e;
#pragma unroll
      for (int off = 32; off > 0; off >>= 1) ssum += __shfl_xor(ssum, off);
      float w = e / ssum;
      if (lane < M_) sWk[lane * K_ + k] = w;
      cur += log1pf(-fminf(w, 1.f - 1e-6f));
    }
  }
  __syncthreads();

  const float* ypB = yp + (size_t)b * N_ * D_;
  float accv[4][K_];
#pragma unroll
  for (int j = 0; j < 4; ++j)
#pragma unroll
    for (int k = 0; k < K_; ++k) accv[j][k] = 0.f;

  for (int m = 0; m < M_; ++m) {
    const int cn = sIdx[m];
    const float* yg = ypB + (size_t)cn * D_;
    float wv[K_];
#pragma unroll
    for (int k = 0; k < K_; ++k) wv[k] = sWk[m * K_ + k];
#pragma unroll
    for (int j = 0; j < 4; ++j) {
      int d = tid + 256 * j;
      if (d < D_) {
        float y = yg[d];
#pragma unroll
        for (int k = 0; k < K_; ++k) accv[j][k] += wv[k] * y;
      }
    }
  }
#pragma unroll
  for (int j = 0; j < 4; ++j) {
    int d = tid + 256 * j;
    if (d < D_) {
#pragma unroll
      for (int k = 0; k < K_; ++k)
        nb[(((size_t)k * B_ + b) * N_ + n) * D_ + d] = accv[j][k];
    }
  }
}

// ---------------------------------------------------------------------------
// Fold as gather: each output pixel of vol k is the average of <=4 covering
// patch entries of nb[k]. Rows/cols >=220 have no covering patch -> 0.
// ---------------------------------------------------------------------------
__global__ __launch_bounds__(256) void fold_k(const float* __restrict__ nb,
                                              float* __restrict__ out) {
  int i = blockIdx.x * 256 + threadIdx.x;
  constexpr int TOT = B_ * K_ * E_ * HW;
  if (i >= TOT) return;
  int w = i % W_;
  int h = (i / W_) % H_;
  int c = (i / HW) % E_;
  int k = (i / (HW * E_)) % K_;
  int b = i / (HW * E_ * K_);
  int q1lo = max(0, (h - 5) / 5), q1hi = min(N1 - 1, h / 5);
  int q2lo = max(0, (w - 5) / 5), q2hi = min(N2 - 1, w / 5);
  float val = 0.f;
  int cnt = 0;
  for (int q1 = q1lo; q1 <= q1hi; ++q1)
    for (int q2 = q2lo; q2 <= q2hi; ++q2) {
      int i0 = h - 5 * q1, j0 = w - 5 * q2;
      int nn = q1 * N2 + q2;
      val += nb[(((size_t)k * B_ + b) * N_ + nn) * D_ + c * 100 + i0 * 10 + j0];
      ++cnt;
    }
  float res = (cnt > 0) ? val / (float)cnt : 0.f;
  out[((size_t)b * (CIN * (K_ + 1)) + CIN + k * E_ + c) * HW + h * W_ + w] = res;
}

__global__ __launch_bounds__(256) void copyx_k(const float* __restrict__ x,
                                               float* __restrict__ out) {
  int i = blockIdx.x * 256 + threadIdx.x;
  constexpr int TOT = B_ * CIN * HW;
  if (i >= TOT) return;
  int b = i / (CIN * HW);
  int r = i % (CIN * HW);
  out[(size_t)b * (CIN * (K_ + 1)) * HW + r] = x[i];
}

extern "C" void kernel_launch(void* const* d_in, const int* in_sizes, int n_in,
                              void* d_out, int out_size, void* d_ws,
                              size_t ws_size, hipStream_t stream) {
  const float* x   = (const float*)d_in[0];
  const float* w1e = (const float*)d_in[1];
  const float* b1e = (const float*)d_in[2];
  const float* w2e = (const float*)d_in[3];
  const float* b2e = (const float*)d_in[4];
  const float* w3e = (const float*)d_in[5];
  const float* b3e = (const float*)d_in[6];
  const float* w1t = (const float*)d_in[7];
  const float* b1t = (const float*)d_in[8];
  const float* w2t = (const float*)d_in[9];
  const float* b2t = (const float*)d_in[10];
  const float* w3t = (const float*)d_in[11];
  const float* b3t = (const float*)d_in[12];

  float* ws  = (float*)d_ws;
  float* out = (float*)d_out;

  float* h1e = ws + OFF_H1E;
  float* h1t = ws + OFF_H1T;
  float* h2e = ws + OFF_H2E;
  float* h2t = ws + OFF_H2T;
  float* nb  = ws + OFF_NB;
  float* xe  = ws + OFF_XE;
  float* ltm = ws + OFF_LTM;
  float* pe  = ws + OFF_PE;
  float* yp  = ws + OFF_YP;
  float* lt  = ws + OFF_LT;
  float* sqv = ws + OFF_SQ;

  dim3 cb(16, 16);
  // conv1 (8 -> 64, relu), both branches
  conv3x3_k<CIN, 16, true><<<dim3(7, 7, B_ * 4), cb, 0, stream>>>(x, w1e, b1e, h1e, F_);
  conv3x3_k<CIN, 16, true><<<dim3(7, 7, B_ * 4), cb, 0, stream>>>(x, w1t, b1t, h1t, F_);
  // conv2 (64 -> 64, relu)
  conv3x3_k<F_, 16, true><<<dim3(7, 7, B_ * 4), cb, 0, stream>>>(h1e, w2e, b2e, h2e, F_);
  conv3x3_k<F_, 16, true><<<dim3(7, 7, B_ * 4), cb, 0, stream>>>(h1t, w2t, b2t, h2t, F_);
  // conv3 (64 -> 8 / 64 -> 1, no relu)
  conv3x3_k<F_, 8, false><<<dim3(7, 7, B_), cb, 0, stream>>>(h2e, w3e, b3e, xe, E_);
  conv3x3_k<F_, 1, false><<<dim3(7, 7, B_), cb, 0, stream>>>(h2t, w3t, b3t, ltm, 1);
  // patches
  constexpr int PT = B_ * N_ * D_;
  patches_k<<<(PT + 255) / 256, 256, 0, stream>>>(xe, pe);
  patches_k<<<(PT + 255) / 256, 256, 0, stream>>>(x, yp);
  // per-patch norms + log-temp means
  ltsq_k<<<B_ * N_, 64, 0, stream>>>(pe, ltm, lt, sqv);
  // attention (dots + K softmax rounds + weighted neighbor sums)
  attn_k<<<dim3(N_, B_), 256, 0, stream>>>(pe, yp, lt, sqv, nb);
  // fold (gather) + passthrough copy of x
  constexpr int FT = B_ * K_ * E_ * HW;
  fold_k<<<(FT + 255) / 256, 256, 0, stream>>>(nb, out);
  constexpr int CT = B_ * CIN * HW;
  copyx_k<<<(CT + 255) / 256, 256, 0, stream>>>(x, out);
}

// Round 2
// 1219.005 us; speedup vs baseline: 1.0125x; 1.0125x over previous
//
#include <hip/hip_runtime.h>
#include <math.h>

namespace {
constexpr int B_ = 2, CIN = 8, H_ = 224, W_ = 224;
constexpr int K_ = 7;
constexpr int F_ = 64, E_ = 8;
constexpr int N1 = 43, N2 = 43, N_ = N1 * N2;   // 1849
constexpr int M_ = 49;                           // candidates per query
constexpr int D_ = 800;                          // patch dim (C*P*P)
constexpr int HW = H_ * W_;
constexpr int NSW = 1856;                        // swizzled grid for n (8*232)

// workspace layout (floats).
// Timeline: h1e/h1t live conv1->conv2; h2e/h2t live conv2->conv3.
// wk written by attn_w (after convs), nb by attn_pv -> both reuse conv scratch.
constexpr size_t FHW = (size_t)B_ * F_ * HW;     // 6,422,528
constexpr size_t OFF_H1E = 0;
constexpr size_t OFF_H1T = OFF_H1E + FHW;
constexpr size_t OFF_H2E = OFF_H1T + FHW;
constexpr size_t OFF_H2T = OFF_H2E + FHW;
constexpr size_t OFF_WK  = 0;                                  // B*N*343
constexpr size_t OFF_NB  = 1280000;                            // > Wk end
constexpr size_t OFF_XE  = OFF_H2T + FHW;
constexpr size_t OFF_LTM = OFF_XE + (size_t)B_ * E_ * HW;
constexpr size_t OFF_PE  = OFF_LTM + (size_t)B_ * HW;
constexpr size_t OFF_YP  = OFF_PE + (size_t)B_ * N_ * D_;
constexpr size_t OFF_LT  = OFF_YP + (size_t)B_ * N_ * D_;
constexpr size_t OFF_SQ  = OFF_LT + (size_t)B_ * N_;

__device__ __forceinline__ int clampi(int v, int lo, int hi) {
  return min(max(v, lo), hi);
}
__device__ __forceinline__ int swiz_n(int xr) { return (xr & 7) * 232 + (xr >> 3); }
} // namespace

// ---------------------------------------------------------------------------
// Direct 3x3 SAME conv, NCHW. TILE x TILE spatial tile per 256-thread block.
// TILE=32 -> 2x2 px/thread, TILE=16 -> 1 px/thread. Weights read directly
// from global via block-uniform indices (scalar loads, K$). CIB=4 input
// planes staged in LDS per barrier round.
// ---------------------------------------------------------------------------
template <int CI, int COG, int TILE, bool RELU>
__global__ __launch_bounds__(256) void conv3x3_k(
    const float* __restrict__ in, const float* __restrict__ wgt,
    const float* __restrict__ bias, float* __restrict__ out, int cout) {
  constexpr int CIB = (CI >= 4) ? 4 : CI;
  constexpr int TP = TILE + 2;
  constexpr int PX = (TILE == 32) ? 2 : 1;
  constexpr int TPT = TILE / PX;  // threads per row = 16

  const int n_cog = cout / COG;
  const int b = blockIdx.z / n_cog;
  const int co0 = (blockIdx.z % n_cog) * COG;
  const int th0 = blockIdx.y * TILE, tw0 = blockIdx.x * TILE;
  const int tid = threadIdx.x;
  const int ty = tid / TPT, tx = tid % TPT;
  const int oy = PX * ty, ox = PX * tx;

  __shared__ float sT[CIB][TP * TP];

  float acc[COG][PX][PX];
#pragma unroll
  for (int c = 0; c < COG; ++c) {
    float bv = bias[co0 + c];
#pragma unroll
    for (int r = 0; r < PX; ++r)
#pragma unroll
      for (int s = 0; s < PX; ++s) acc[c][r][s] = bv;
  }

  for (int cb = 0; cb < CI; cb += CIB) {
    __syncthreads();
    for (int s = tid; s < CIB * TP * TP; s += 256) {
      int pl = s / (TP * TP), rem = s - pl * (TP * TP);
      int lr = rem / TP, lc = rem - lr * TP;
      int gh = th0 + lr - 1, gw = tw0 + lc - 1;
      float v = 0.f;
      if (gh >= 0 && gh < H_ && gw >= 0 && gw < W_)
        v = in[((size_t)b * CI + cb + pl) * HW + gh * W_ + gw];
      sT[pl][rem] = v;
    }
    __syncthreads();
#pragma unroll
    for (int ci = 0; ci < CIB; ++ci) {
      float iv[PX + 2][PX + 2];
#pragma unroll
      for (int r = 0; r < PX + 2; ++r)
#pragma unroll
        for (int s = 0; s < PX + 2; ++s)
          iv[r][s] = sT[ci][(oy + r) * TP + ox + s];
#pragma unroll
      for (int c = 0; c < COG; ++c) {
        const float* wp = &wgt[((size_t)(co0 + c) * CI + cb + ci) * 9];
        float w0 = wp[0], w1 = wp[1], w2 = wp[2], w3 = wp[3], w4 = wp[4];
        float w5 = wp[5], w6 = wp[6], w7 = wp[7], w8 = wp[8];
#pragma unroll
        for (int dy = 0; dy < PX; ++dy)
#pragma unroll
          for (int dx = 0; dx < PX; ++dx) {
            acc[c][dy][dx] += iv[dy + 0][dx + 0] * w0 + iv[dy + 0][dx + 1] * w1 +
                              iv[dy + 0][dx + 2] * w2 + iv[dy + 1][dx + 0] * w3 +
                              iv[dy + 1][dx + 1] * w4 + iv[dy + 1][dx + 2] * w5 +
                              iv[dy + 2][dx + 0] * w6 + iv[dy + 2][dx + 1] * w7 +
                              iv[dy + 2][dx + 2] * w8;
          }
      }
    }
  }

#pragma unroll
  for (int c = 0; c < COG; ++c)
#pragma unroll
    for (int dy = 0; dy < PX; ++dy)
#pragma unroll
      for (int dx = 0; dx < PX; ++dx) {
        int h = th0 + oy + dy, w = tw0 + ox + dx;
        float v = acc[c][dy][dx];
        if (RELU) v = fmaxf(v, 0.f);
        out[((size_t)b * cout + co0 + c) * HW + h * W_ + w] = v;
      }
}

// ---------------------------------------------------------------------------
// Patch extraction: dst[b, n, c*100 + i*10 + j] = src[b, c, 5*q1+i, 5*q2+j]
// ---------------------------------------------------------------------------
__global__ __launch_bounds__(256) void patches_k(const float* __restrict__ src,
                                                 float* __restrict__ dst) {
  int i = blockIdx.x * 256 + threadIdx.x;
  constexpr int TOT = B_ * N_ * D_;
  if (i >= TOT) return;
  int d = i % D_;
  int n = (i / D_) % N_;
  int b = i / (D_ * N_);
  int c = d / 100;
  int rr = (d / 10) % 10;
  int cc = d % 10;
  int q1 = n / N2, q2 = n % N2;
  dst[i] = src[((size_t)(b * 8 + c) * H_ + q1 * 5 + rr) * W_ + q2 * 5 + cc];
}

// ---------------------------------------------------------------------------
// Per-(b,n): sq = ||pe||^2 ; lt = mean of 10x10 log_temp patch. 1 wave each.
// ---------------------------------------------------------------------------
__global__ __launch_bounds__(64) void ltsq_k(const float* __restrict__ pe,
                                             const float* __restrict__ ltmap,
                                             float* __restrict__ lt,
                                             float* __restrict__ sq) {
  int bn = blockIdx.x;
  int b = bn / N_, n = bn % N_;
  int lane = threadIdx.x;
  const float* p = pe + (size_t)bn * D_;
  float s = 0.f;
  for (int i = lane; i < D_; i += 64) {
    float v = p[i];
    s += v * v;
  }
#pragma unroll
  for (int off = 32; off > 0; off >>= 1) s += __shfl_xor(s, off);
  int q1 = n / N2, q2 = n % N2;
  const float* lm = ltmap + (size_t)b * HW;
  float t = 0.f;
  for (int i = lane; i < 100; i += 64)
    t += lm[(q1 * 5 + i / 10) * W_ + q2 * 5 + i % 10];
#pragma unroll
  for (int off = 32; off > 0; off >>= 1) t += __shfl_xor(t, off);
  if (lane == 0) {
    sq[bn] = s;
    lt[bn] = t * 0.01f;
  }
}

// ---------------------------------------------------------------------------
// attn stage 1: one wave per (b,n). Query row in registers, 49 dots with
// arithmetic candidate indices, K softmax rounds in-wave, write Wk[b,n,m,k].
// ---------------------------------------------------------------------------
__global__ __launch_bounds__(64) void attn_w_k(const float* __restrict__ pe,
                                               const float* __restrict__ lt,
                                               const float* __restrict__ sq,
                                               float* __restrict__ wk) {
  const int n = swiz_n(blockIdx.x);
  if (n >= N_) return;
  const int b = blockIdx.y;
  const int lane = threadIdx.x;
  const int q1 = n / N2, q2 = n % N2;

  const float* peB = pe + (size_t)b * N_ * D_;
  const float* qrow = peB + (size_t)n * D_;
  float q[13];
#pragma unroll
  for (int t = 0; t < 13; ++t) {
    int s = t * 64 + lane;
    q[t] = (s < D_) ? qrow[s] : 0.f;
  }

  __shared__ float sG[M_];

  for (int o1 = 0; o1 < 7; ++o1) {
    int c1 = clampi(q1 + o1 - 3, 0, N1 - 1);
    const float* rowb = peB + (size_t)(c1 * N2) * D_;
#pragma unroll
    for (int o2 = 0; o2 < 7; ++o2) {
      int c2 = clampi(q2 + o2 - 3, 0, N2 - 1);
      const float* crow = rowb + (size_t)c2 * D_;
      float a = 0.f;
#pragma unroll
      for (int t = 0; t < 13; ++t) {
        float v;
        if (t < 12) v = crow[t * 64 + lane];
        else v = (lane < 32) ? crow[768 + lane] : 0.f;
        a += q[t] * v;
      }
#pragma unroll
      for (int off = 32; off > 0; off >>= 1) a += __shfl_xor(a, off);
      if (lane == 0) sG[o1 * 7 + o2] = a;
    }
  }
  __syncthreads();

  const float sqn = sq[b * N_ + n];
  const float itemp = expf(-lt[b * N_ + n]);
  float cur = -INFINITY;
  if (lane < M_) {
    int c1 = clampi(q1 + lane / 7 - 3, 0, N1 - 1);
    int c2 = clampi(q2 + lane % 7 - 3, 0, N2 - 1);
    int cn = c1 * N2 + c2;
    float Dv = -(sqn + sq[b * N_ + cn] - 2.f * sG[lane]);
    cur = (cn == n) ? -1e9f : Dv * itemp;
  }
  float* wrow = wk + (size_t)(b * N_ + n) * (M_ * K_);
#pragma unroll
  for (int k = 0; k < K_; ++k) {
    float mx = cur;
#pragma unroll
    for (int off = 32; off > 0; off >>= 1) mx = fmaxf(mx, __shfl_xor(mx, off));
    float e = (lane < M_) ? expf(cur - mx) : 0.f;
    float ssum = e;
#pragma unroll
    for (int off = 32; off > 0; off >>= 1) ssum += __shfl_xor(ssum, off);
    float w = e / ssum;
    if (lane < M_) wrow[lane * K_ + k] = w;
    cur += log1pf(-fminf(w, 1.f - 1e-6f));
  }
}

// ---------------------------------------------------------------------------
// attn stage 2: one wave per (b, n, d-slice of 64). Weights via scalar loads
// (block-uniform), 7 accumulators, 49 independent coalesced y loads.
// ---------------------------------------------------------------------------
__global__ __launch_bounds__(64) void attn_pv_k(const float* __restrict__ yp,
                                                const float* __restrict__ wk,
                                                float* __restrict__ nb) {
  const int n = swiz_n(blockIdx.x);
  if (n >= N_) return;
  const int b = blockIdx.z;
  const int d = blockIdx.y * 64 + threadIdx.x;
  const bool valid = d < D_;
  const int q1 = n / N2, q2 = n % N2;

  const float* ypB = yp + (size_t)b * N_ * D_;
  const float* wrow = wk + (size_t)(b * N_ + n) * (M_ * K_);

  float acc[K_];
#pragma unroll
  for (int k = 0; k < K_; ++k) acc[k] = 0.f;

#pragma unroll
  for (int o1 = 0; o1 < 7; ++o1) {
    int c1 = clampi(q1 + o1 - 3, 0, N1 - 1);
#pragma unroll
    for (int o2 = 0; o2 < 7; ++o2) {
      int c2 = clampi(q2 + o2 - 3, 0, N2 - 1);
      int cn = c1 * N2 + c2;
      float y = valid ? ypB[(size_t)cn * D_ + d] : 0.f;
      const int m = o1 * 7 + o2;
#pragma unroll
      for (int k = 0; k < K_; ++k) acc[k] += wrow[m * K_ + k] * y;
    }
  }
  if (valid) {
#pragma unroll
    for (int k = 0; k < K_; ++k)
      nb[(((size_t)k * B_ + b) * N_ + n) * D_ + d] = acc[k];
  }
}

// ---------------------------------------------------------------------------
// Fused output: channels 0..7 copy x; channels 8..63 fold-gather from nb.
// ---------------------------------------------------------------------------
__global__ __launch_bounds__(256) void foldcopy_k(const float* __restrict__ x,
                                                  const float* __restrict__ nb,
                                                  float* __restrict__ out) {
  int i = blockIdx.x * 256 + threadIdx.x;
  constexpr int CT = CIN * (K_ + 1);  // 64
  constexpr int TOT = B_ * CT * HW;
  if (i >= TOT) return;
  int w = i % W_;
  int h = (i / W_) % H_;
  int c64 = (i / HW) % CT;
  int b = i / (HW * CT);
  if (c64 < CIN) {
    out[i] = x[((size_t)b * CIN + c64) * HW + h * W_ + w];
    return;
  }
  int k = (c64 - CIN) >> 3, c = (c64 - CIN) & 7;
  int q1lo = max(0, (h - 5) / 5), q1hi = min(N1 - 1, h / 5);
  int q2lo = max(0, (w - 5) / 5), q2hi = min(N2 - 1, w / 5);
  float val = 0.f;
  int cnt = 0;
  for (int q1 = q1lo; q1 <= q1hi; ++q1)
    for (int q2 = q2lo; q2 <= q2hi; ++q2) {
      int i0 = h - 5 * q1, j0 = w - 5 * q2;
      int nn = q1 * N2 + q2;
      val += nb[(((size_t)k * B_ + b) * N_ + nn) * D_ + c * 100 + i0 * 10 + j0];
      ++cnt;
    }
  out[i] = (cnt > 0) ? val / (float)cnt : 0.f;
}

extern "C" void kernel_launch(void* const* d_in, const int* in_sizes, int n_in,
                              void* d_out, int out_size, void* d_ws,
                              size_t ws_size, hipStream_t stream) {
  const float* x   = (const float*)d_in[0];
  const float* w1e = (const float*)d_in[1];
  const float* b1e = (const float*)d_in[2];
  const float* w2e = (const float*)d_in[3];
  const float* b2e = (const float*)d_in[4];
  const float* w3e = (const float*)d_in[5];
  const float* b3e = (const float*)d_in[6];
  const float* w1t = (const float*)d_in[7];
  const float* b1t = (const float*)d_in[8];
  const float* w2t = (const float*)d_in[9];
  const float* b2t = (const float*)d_in[10];
  const float* w3t = (const float*)d_in[11];
  const float* b3t = (const float*)d_in[12];

  float* ws  = (float*)d_ws;
  float* out = (float*)d_out;

  float* h1e = ws + OFF_H1E;
  float* h1t = ws + OFF_H1T;
  float* h2e = ws + OFF_H2E;
  float* h2t = ws + OFF_H2T;
  float* wkb = ws + OFF_WK;
  float* nb  = ws + OFF_NB;
  float* xe  = ws + OFF_XE;
  float* ltm = ws + OFF_LTM;
  float* pe  = ws + OFF_PE;
  float* yp  = ws + OFF_YP;
  float* lt  = ws + OFF_LT;
  float* sqv = ws + OFF_SQ;

  // conv1 (8 -> 64, relu): COG=8 -> grid 7x7x16 = 784 blocks per branch
  conv3x3_k<CIN, 8, 32, true><<<dim3(7, 7, 16), 256, 0, stream>>>(x, w1e, b1e, h1e, F_);
  conv3x3_k<CIN, 8, 32, true><<<dim3(7, 7, 16), 256, 0, stream>>>(x, w1t, b1t, h1t, F_);
  // conv2 (64 -> 64, relu)
  conv3x3_k<F_, 8, 32, true><<<dim3(7, 7, 16), 256, 0, stream>>>(h1e, w2e, b2e, h2e, F_);
  conv3x3_k<F_, 8, 32, true><<<dim3(7, 7, 16), 256, 0, stream>>>(h1t, w2t, b2t, h2t, F_);
  // conv3 (64 -> 8 / 64 -> 1): 16-tile for parallelism (14x14 grid)
  conv3x3_k<F_, 8, 16, false><<<dim3(14, 14, 2), 256, 0, stream>>>(h2e, w3e, b3e, xe, E_);
  conv3x3_k<F_, 1, 16, false><<<dim3(14, 14, 2), 256, 0, stream>>>(h2t, w3t, b3t, ltm, 1);
  // patches
  constexpr int PT = B_ * N_ * D_;
  patches_k<<<(PT + 255) / 256, 256, 0, stream>>>(xe, pe);
  patches_k<<<(PT + 255) / 256, 256, 0, stream>>>(x, yp);
  // per-patch norms + log-temp means
  ltsq_k<<<B_ * N_, 64, 0, stream>>>(pe, ltm, lt, sqv);
  // attention stage 1: weights
  attn_w_k<<<dim3(NSW, B_), 64, 0, stream>>>(pe, lt, sqv, wkb);
  // attention stage 2: weighted neighbor sums (d split into 13 slices)
  attn_pv_k<<<dim3(NSW, 13, B_), 64, 0, stream>>>(yp, wkb, nb);
  // fused fold + x passthrough
  constexpr int FT = B_ * CIN * (K_ + 1) * HW;
  foldcopy_k<<<(FT + 255) / 256, 256, 0, stream>>>(x, nb, out);
}

// Round 3
// 946.835 us; speedup vs baseline: 1.3035x; 1.2875x over previous
//
#include <hip/hip_runtime.h>
#include <math.h>

namespace {
constexpr int B_ = 2, CIN = 8, H_ = 224, W_ = 224;
constexpr int K_ = 7;
constexpr int F_ = 64, E_ = 8;
constexpr int N1 = 43, N2 = 43, N_ = N1 * N2;   // 1849
constexpr int M_ = 49;                           // candidates per query
constexpr int D_ = 800;                          // patch dim (C*P*P)
constexpr int HW = H_ * W_;
constexpr int NSW = 1856;                        // swizzled grid for n (8*232)

// workspace layout (floats).
constexpr size_t FHW = (size_t)B_ * F_ * HW;     // 6,422,528
constexpr size_t OFF_H1E = 0;
constexpr size_t OFF_H1T = OFF_H1E + FHW;
constexpr size_t OFF_H2E = OFF_H1T + FHW;
constexpr size_t OFF_H2T = OFF_H2E + FHW;
constexpr size_t OFF_WK  = 0;                                  // B*N*343
constexpr size_t OFF_NB  = 1280000;                            // > Wk end
constexpr size_t OFF_XE  = OFF_H2T + FHW;
constexpr size_t OFF_LTM = OFF_XE + (size_t)B_ * E_ * HW;
constexpr size_t OFF_PE  = OFF_LTM + (size_t)B_ * HW;
constexpr size_t OFF_YP  = OFF_PE + (size_t)B_ * N_ * D_;
constexpr size_t OFF_LT  = OFF_YP + (size_t)B_ * N_ * D_;
constexpr size_t OFF_SQ  = OFF_LT + (size_t)B_ * N_;

__device__ __forceinline__ int clampi(int v, int lo, int hi) {
  return min(max(v, lo), hi);
}
__device__ __forceinline__ int swiz_n(int xr) { return (xr & 7) * 232 + (xr >> 3); }
} // namespace

// ---------------------------------------------------------------------------
// 3x3 SAME conv, NCHW, 32x32 tile, 256 threads, 4x1 px/thread (ox=tx stride-1
// -> conflict-free LDS). Weights staged in LDS once (pad 9->12, read as 3x
// b128 broadcast). Input planes staged CIB=4/round with register prefetch of
// the next round so the barrier only waits on ds_write.
// ---------------------------------------------------------------------------
template <int CI, int COG, bool RELU>
__global__ __launch_bounds__(256) void conv32_k(
    const float* __restrict__ in, const float* __restrict__ wgt,
    const float* __restrict__ bias, float* __restrict__ out, int cout) {
  constexpr int CIB = (CI >= 4) ? 4 : CI;
  constexpr int TP = 34;
  constexpr int NST = CIB * TP * TP;
  constexpr int NLD = (NST + 255) / 256;

  const int cog = blockIdx.x;      // co-group FASTEST -> L2 tile reuse
  const int tile = blockIdx.y;     // 0..48
  const int b = blockIdx.z;
  const int co0 = cog * COG;
  const int th0 = (tile / 7) * 32, tw0 = (tile % 7) * 32;
  const int tid = threadIdx.x;
  const int tx = tid & 31, ty = tid >> 5;   // ty 0..7, rows 4*ty..4*ty+3

  __shared__ float sW[COG * CI * 12];
  __shared__ float sT[CIB][TP * TP];

  for (int s = tid; s < COG * CI * 12; s += 256) {
    int c = s / (CI * 12);
    int rem = s - c * (CI * 12);
    int ci = rem / 12, r = rem - ci * 12;
    sW[s] = (r < 9) ? wgt[((size_t)(co0 + c) * CI + ci) * 9 + r] : 0.f;
  }

  // staging offsets (constant across rounds)
  int po[NLD];
  unsigned okm = 0;
#pragma unroll
  for (int j = 0; j < NLD; ++j) {
    int s = tid + 256 * j;
    int pl = s / (TP * TP), rem = s - pl * (TP * TP);
    int lr = rem / TP, lc = rem - lr * TP;
    int gh = th0 + lr - 1, gw = tw0 + lc - 1;
    bool ok = (s < NST) && gh >= 0 && gh < H_ && gw >= 0 && gw < W_;
    po[j] = ok ? (pl * HW + gh * W_ + gw) : 0;
    if (ok) okm |= (1u << j);
  }

  const float* inB = in + (size_t)b * CI * HW;
  float stg[NLD];
#pragma unroll
  for (int j = 0; j < NLD; ++j) {
    float v = inB[po[j]];
    stg[j] = ((okm >> j) & 1) ? v : 0.f;
  }

  float acc[COG][4];
#pragma unroll
  for (int c = 0; c < COG; ++c) {
    float bv = bias[co0 + c];
#pragma unroll
    for (int r = 0; r < 4; ++r) acc[c][r] = bv;
  }

  for (int cb = 0; cb < CI; cb += CIB) {
    __syncthreads();
#pragma unroll
    for (int j = 0; j < NLD; ++j) {
      int s = tid + 256 * j;
      if (s < NST) ((float*)sT)[s] = stg[j];
    }
    __syncthreads();
    if (cb + CIB < CI) {
      const float* inN = inB + (size_t)(cb + CIB) * HW;
#pragma unroll
      for (int j = 0; j < NLD; ++j) {
        float v = inN[po[j]];
        stg[j] = ((okm >> j) & 1) ? v : 0.f;
      }
    }
#pragma unroll
    for (int ci = 0; ci < CIB; ++ci) {
      float iv[6][3];
#pragma unroll
      for (int r = 0; r < 6; ++r)
#pragma unroll
        for (int s2 = 0; s2 < 3; ++s2)
          iv[r][s2] = sT[ci][(4 * ty + r) * TP + tx + s2];
#pragma unroll
      for (int c = 0; c < COG; ++c) {
        const float4* wp = (const float4*)&sW[(c * CI + cb + ci) * 12];
        float4 wa = wp[0], wb = wp[1], wc = wp[2];
#pragma unroll
        for (int dy = 0; dy < 4; ++dy) {
          acc[c][dy] += iv[dy + 0][0] * wa.x + iv[dy + 0][1] * wa.y +
                        iv[dy + 0][2] * wa.z + iv[dy + 1][0] * wa.w +
                        iv[dy + 1][1] * wb.x + iv[dy + 1][2] * wb.y +
                        iv[dy + 2][0] * wb.z + iv[dy + 2][1] * wb.w +
                        iv[dy + 2][2] * wc.x;
        }
      }
    }
  }

#pragma unroll
  for (int c = 0; c < COG; ++c)
#pragma unroll
    for (int dy = 0; dy < 4; ++dy) {
      int h = th0 + 4 * ty + dy, w = tw0 + tx;
      float v = acc[c][dy];
      if (RELU) v = fmaxf(v, 0.f);
      out[((size_t)b * cout + co0 + c) * HW + h * W_ + w] = v;
    }
}

// ---------------------------------------------------------------------------
// Same structure, 16x16 tile, 1 px/thread (for the small conv3 outputs).
// ---------------------------------------------------------------------------
template <int CI, int COG, bool RELU>
__global__ __launch_bounds__(256) void conv16_k(
    const float* __restrict__ in, const float* __restrict__ wgt,
    const float* __restrict__ bias, float* __restrict__ out, int cout) {
  constexpr int CIB = (CI >= 4) ? 4 : CI;
  constexpr int TP = 18;
  constexpr int NST = CIB * TP * TP;
  constexpr int NLD = (NST + 255) / 256;

  const int cog = blockIdx.x;
  const int tile = blockIdx.y;  // 0..195
  const int b = blockIdx.z;
  const int co0 = cog * COG;
  const int th0 = (tile / 14) * 16, tw0 = (tile % 14) * 16;
  const int tid = threadIdx.x;
  const int tx = tid & 15, ty = tid >> 4;  // 16x16

  __shared__ float sW[COG * CI * 12];
  __shared__ float sT[CIB][TP * TP];

  for (int s = tid; s < COG * CI * 12; s += 256) {
    int c = s / (CI * 12);
    int rem = s - c * (CI * 12);
    int ci = rem / 12, r = rem - ci * 12;
    sW[s] = (r < 9) ? wgt[((size_t)(co0 + c) * CI + ci) * 9 + r] : 0.f;
  }

  int po[NLD];
  unsigned okm = 0;
#pragma unroll
  for (int j = 0; j < NLD; ++j) {
    int s = tid + 256 * j;
    int pl = s / (TP * TP), rem = s - pl * (TP * TP);
    int lr = rem / TP, lc = rem - lr * TP;
    int gh = th0 + lr - 1, gw = tw0 + lc - 1;
    bool ok = (s < NST) && gh >= 0 && gh < H_ && gw >= 0 && gw < W_;
    po[j] = ok ? (pl * HW + gh * W_ + gw) : 0;
    if (ok) okm |= (1u << j);
  }

  const float* inB = in + (size_t)b * CI * HW;
  float stg[NLD];
#pragma unroll
  for (int j = 0; j < NLD; ++j) {
    float v = inB[po[j]];
    stg[j] = ((okm >> j) & 1) ? v : 0.f;
  }

  float acc[COG];
#pragma unroll
  for (int c = 0; c < COG; ++c) acc[c] = bias[co0 + c];

  for (int cb = 0; cb < CI; cb += CIB) {
    __syncthreads();
#pragma unroll
    for (int j = 0; j < NLD; ++j) {
      int s = tid + 256 * j;
      if (s < NST) ((float*)sT)[s] = stg[j];
    }
    __syncthreads();
    if (cb + CIB < CI) {
      const float* inN = inB + (size_t)(cb + CIB) * HW;
#pragma unroll
      for (int j = 0; j < NLD; ++j) {
        float v = inN[po[j]];
        stg[j] = ((okm >> j) & 1) ? v : 0.f;
      }
    }
#pragma unroll
    for (int ci = 0; ci < CIB; ++ci) {
      float iv[3][3];
#pragma unroll
      for (int r = 0; r < 3; ++r)
#pragma unroll
        for (int s2 = 0; s2 < 3; ++s2)
          iv[r][s2] = sT[ci][(ty + r) * TP + tx + s2];
#pragma unroll
      for (int c = 0; c < COG; ++c) {
        const float4* wp = (const float4*)&sW[(c * CI + cb + ci) * 12];
        float4 wa = wp[0], wb = wp[1], wc = wp[2];
        acc[c] += iv[0][0] * wa.x + iv[0][1] * wa.y + iv[0][2] * wa.z +
                  iv[1][0] * wa.w + iv[1][1] * wb.x + iv[1][2] * wb.y +
                  iv[2][0] * wb.z + iv[2][1] * wb.w + iv[2][2] * wc.x;
      }
    }
  }

#pragma unroll
  for (int c = 0; c < COG; ++c) {
    int h = th0 + ty, w = tw0 + tx;
    float v = acc[c];
    if (RELU) v = fmaxf(v, 0.f);
    out[((size_t)b * cout + co0 + c) * HW + h * W_ + w] = v;
  }
}

// ---------------------------------------------------------------------------
// Patch extraction: dst[b, n, c*100 + i*10 + j] = src[b, c, 5*q1+i, 5*q2+j]
// ---------------------------------------------------------------------------
__global__ __launch_bounds__(256) void patches_k(const float* __restrict__ src,
                                                 float* __restrict__ dst) {
  int i = blockIdx.x * 256 + threadIdx.x;
  constexpr int TOT = B_ * N_ * D_;
  if (i >= TOT) return;
  int d = i % D_;
  int n = (i / D_) % N_;
  int b = i / (D_ * N_);
  int c = d / 100;
  int rr = (d / 10) % 10;
  int cc = d % 10;
  int q1 = n / N2, q2 = n % N2;
  dst[i] = src[((size_t)(b * 8 + c) * H_ + q1 * 5 + rr) * W_ + q2 * 5 + cc];
}

// ---------------------------------------------------------------------------
// Per-(b,n): sq = ||pe||^2 ; lt = mean of 10x10 log_temp patch. 1 wave each.
// ---------------------------------------------------------------------------
__global__ __launch_bounds__(64) void ltsq_k(const float* __restrict__ pe,
                                             const float* __restrict__ ltmap,
                                             float* __restrict__ lt,
                                             float* __restrict__ sq) {
  int bn = blockIdx.x;
  int b = bn / N_, n = bn % N_;
  int lane = threadIdx.x;
  const float* p = pe + (size_t)bn * D_;
  float s = 0.f;
  for (int i = lane; i < D_; i += 64) {
    float v = p[i];
    s += v * v;
  }
#pragma unroll
  for (int off = 32; off > 0; off >>= 1) s += __shfl_xor(s, off);
  int q1 = n / N2, q2 = n % N2;
  const float* lm = ltmap + (size_t)b * HW;
  float t = 0.f;
  for (int i = lane; i < 100; i += 64)
    t += lm[(q1 * 5 + i / 10) * W_ + q2 * 5 + i % 10];
#pragma unroll
  for (int off = 32; off > 0; off >>= 1) t += __shfl_xor(t, off);
  if (lane == 0) {
    sq[bn] = s;
    lt[bn] = t * 0.01f;
  }
}

// ---------------------------------------------------------------------------
// attn stage 1: one wave per (b,n). Query row in registers, 49 dots,
// K softmax rounds in-wave, write Wk[b,n,m,k].
// ---------------------------------------------------------------------------
__global__ __launch_bounds__(64) void attn_w_k(const float* __restrict__ pe,
                                               const float* __restrict__ lt,
                                               const float* __restrict__ sq,
                                               float* __restrict__ wk) {
  const int n = swiz_n(blockIdx.x);
  if (n >= N_) return;
  const int b = blockIdx.y;
  const int lane = threadIdx.x;
  const int q1 = n / N2, q2 = n % N2;

  const float* peB = pe + (size_t)b * N_ * D_;
  const float* qrow = peB + (size_t)n * D_;
  float q[13];
#pragma unroll
  for (int t = 0; t < 13; ++t) {
    int s = t * 64 + lane;
    q[t] = (s < D_) ? qrow[s] : 0.f;
  }

  __shared__ float sG[M_];

  for (int o1 = 0; o1 < 7; ++o1) {
    int c1 = clampi(q1 + o1 - 3, 0, N1 - 1);
    const float* rowb = peB + (size_t)(c1 * N2) * D_;
#pragma unroll
    for (int o2 = 0; o2 < 7; ++o2) {
      int c2 = clampi(q2 + o2 - 3, 0, N2 - 1);
      const float* crow = rowb + (size_t)c2 * D_;
      float a = 0.f;
#pragma unroll
      for (int t = 0; t < 13; ++t) {
        float v;
        if (t < 12) v = crow[t * 64 + lane];
        else v = (lane < 32) ? crow[768 + lane] : 0.f;
        a += q[t] * v;
      }
#pragma unroll
      for (int off = 32; off > 0; off >>= 1) a += __shfl_xor(a, off);
      if (lane == 0) sG[o1 * 7 + o2] = a;
    }
  }
  __syncthreads();

  const float sqn = sq[b * N_ + n];
  const float itemp = expf(-lt[b * N_ + n]);
  float cur = -INFINITY;
  if (lane < M_) {
    int c1 = clampi(q1 + lane / 7 - 3, 0, N1 - 1);
    int c2 = clampi(q2 + lane % 7 - 3, 0, N2 - 1);
    int cn = c1 * N2 + c2;
    float Dv = -(sqn + sq[b * N_ + cn] - 2.f * sG[lane]);
    cur = (cn == n) ? -1e9f : Dv * itemp;
  }
  float* wrow = wk + (size_t)(b * N_ + n) * (M_ * K_);
#pragma unroll
  for (int k = 0; k < K_; ++k) {
    float mx = cur;
#pragma unroll
    for (int off = 32; off > 0; off >>= 1) mx = fmaxf(mx, __shfl_xor(mx, off));
    float e = (lane < M_) ? expf(cur - mx) : 0.f;
    float ssum = e;
#pragma unroll
    for (int off = 32; off > 0; off >>= 1) ssum += __shfl_xor(ssum, off);
    float w = e / ssum;
    if (lane < M_) wrow[lane * K_ + k] = w;
    cur += log1pf(-fminf(w, 1.f - 1e-6f));
  }
}

// ---------------------------------------------------------------------------
// attn stage 2: one wave per (b, n, d-slice of 64). Weights via scalar loads
// (block-uniform), 7 accumulators, 49 independent coalesced y loads.
// ---------------------------------------------------------------------------
__global__ __launch_bounds__(64) void attn_pv_k(const float* __restrict__ yp,
                                                const float* __restrict__ wk,
                                                float* __restrict__ nb) {
  const int n = swiz_n(blockIdx.x);
  if (n >= N_) return;
  const int b = blockIdx.z;
  const int d = blockIdx.y * 64 + threadIdx.x;
  const bool valid = d < D_;
  const int q1 = n / N2, q2 = n % N2;

  const float* ypB = yp + (size_t)b * N_ * D_;
  const float* wrow = wk + (size_t)(b * N_ + n) * (M_ * K_);

  float acc[K_];
#pragma unroll
  for (int k = 0; k < K_; ++k) acc[k] = 0.f;

#pragma unroll
  for (int o1 = 0; o1 < 7; ++o1) {
    int c1 = clampi(q1 + o1 - 3, 0, N1 - 1);
#pragma unroll
    for (int o2 = 0; o2 < 7; ++o2) {
      int c2 = clampi(q2 + o2 - 3, 0, N2 - 1);
      int cn = c1 * N2 + c2;
      float y = valid ? ypB[(size_t)cn * D_ + d] : 0.f;
      const int m = o1 * 7 + o2;
#pragma unroll
      for (int k = 0; k < K_; ++k) acc[k] += wrow[m * K_ + k] * y;
    }
  }
  if (valid) {
#pragma unroll
    for (int k = 0; k < K_; ++k)
      nb[(((size_t)k * B_ + b) * N_ + n) * D_ + d] = acc[k];
  }
}

// ---------------------------------------------------------------------------
// Fused output: channels 0..7 copy x; channels 8..63 fold-gather from nb.
// ---------------------------------------------------------------------------
__global__ __launch_bounds__(256) void foldcopy_k(const float* __restrict__ x,
                                                  const float* __restrict__ nb,
                                                  float* __restrict__ out) {
  int i = blockIdx.x * 256 + threadIdx.x;
  constexpr int CT = CIN * (K_ + 1);  // 64
  constexpr int TOT = B_ * CT * HW;
  if (i >= TOT) return;
  int w = i % W_;
  int h = (i / W_) % H_;
  int c64 = (i / HW) % CT;
  int b = i / (HW * CT);
  if (c64 < CIN) {
    out[i] = x[((size_t)b * CIN + c64) * HW + h * W_ + w];
    return;
  }
  int k = (c64 - CIN) >> 3, c = (c64 - CIN) & 7;
  int q1lo = max(0, (h - 5) / 5), q1hi = min(N1 - 1, h / 5);
  int q2lo = max(0, (w - 5) / 5), q2hi = min(N2 - 1, w / 5);
  float val = 0.f;
  int cnt = 0;
  for (int q1 = q1lo; q1 <= q1hi; ++q1)
    for (int q2 = q2lo; q2 <= q2hi; ++q2) {
      int i0 = h - 5 * q1, j0 = w - 5 * q2;
      int nn = q1 * N2 + q2;
      val += nb[(((size_t)k * B_ + b) * N_ + nn) * D_ + c * 100 + i0 * 10 + j0];
      ++cnt;
    }
  out[i] = (cnt > 0) ? val / (float)cnt : 0.f;
}

extern "C" void kernel_launch(void* const* d_in, const int* in_sizes, int n_in,
                              void* d_out, int out_size, void* d_ws,
                              size_t ws_size, hipStream_t stream) {
  const float* x   = (const float*)d_in[0];
  const float* w1e = (const float*)d_in[1];
  const float* b1e = (const float*)d_in[2];
  const float* w2e = (const float*)d_in[3];
  const float* b2e = (const float*)d_in[4];
  const float* w3e = (const float*)d_in[5];
  const float* b3e = (const float*)d_in[6];
  const float* w1t = (const float*)d_in[7];
  const float* b1t = (const float*)d_in[8];
  const float* w2t = (const float*)d_in[9];
  const float* b2t = (const float*)d_in[10];
  const float* w3t = (const float*)d_in[11];
  const float* b3t = (const float*)d_in[12];

  float* ws  = (float*)d_ws;
  float* out = (float*)d_out;

  float* h1e = ws + OFF_H1E;
  float* h1t = ws + OFF_H1T;
  float* h2e = ws + OFF_H2E;
  float* h2t = ws + OFF_H2T;
  float* wkb = ws + OFF_WK;
  float* nb  = ws + OFF_NB;
  float* xe  = ws + OFF_XE;
  float* ltm = ws + OFF_LTM;
  float* pe  = ws + OFF_PE;
  float* yp  = ws + OFF_YP;
  float* lt  = ws + OFF_LT;
  float* sqv = ws + OFF_SQ;

  // conv1 (8 -> 64, relu): grid (cog=8 fastest, 49 tiles, B)
  conv32_k<CIN, 8, true><<<dim3(8, 49, B_), 256, 0, stream>>>(x, w1e, b1e, h1e, F_);
  conv32_k<CIN, 8, true><<<dim3(8, 49, B_), 256, 0, stream>>>(x, w1t, b1t, h1t, F_);
  // conv2 (64 -> 64, relu)
  conv32_k<F_, 8, true><<<dim3(8, 49, B_), 256, 0, stream>>>(h1e, w2e, b2e, h2e, F_);
  conv32_k<F_, 8, true><<<dim3(8, 49, B_), 256, 0, stream>>>(h1t, w2t, b2t, h2t, F_);
  // conv3 (64 -> 8 / 64 -> 1): 16-tile, 196 tiles
  conv16_k<F_, 8, false><<<dim3(1, 196, B_), 256, 0, stream>>>(h2e, w3e, b3e, xe, E_);
  conv16_k<F_, 1, false><<<dim3(1, 196, B_), 256, 0, stream>>>(h2t, w3t, b3t, ltm, 1);
  // patches
  constexpr int PT = B_ * N_ * D_;
  patches_k<<<(PT + 255) / 256, 256, 0, stream>>>(xe, pe);
  patches_k<<<(PT + 255) / 256, 256, 0, stream>>>(x, yp);
  // per-patch norms + log-temp means
  ltsq_k<<<B_ * N_, 64, 0, stream>>>(pe, ltm, lt, sqv);
  // attention stage 1: weights
  attn_w_k<<<dim3(NSW, B_), 64, 0, stream>>>(pe, lt, sqv, wkb);
  // attention stage 2: weighted neighbor sums (d split into 13 slices)
  attn_pv_k<<<dim3(NSW, 13, B_), 64, 0, stream>>>(yp, wkb, nb);
  // fused fold + x passthrough
  constexpr int FT = B_ * CIN * (K_ + 1) * HW;
  foldcopy_k<<<(FT + 255) / 256, 256, 0, stream>>>(x, nb, out);
}